// Round 21
// baseline (178.537 us; speedup 1.0000x reference)
//
#include <hip/hip_runtime.h>
#include <stdint.h>

// Problem constants
#define T_DIM 2048
#define B_DIM 4
#define D_DIM 1024
#define H_NUM 16
#define HD 64
#define MROWS (T_DIM * B_DIM)     // 8192 flattened (t*B+b) rows
#define QKV_N (3 * D_DIM)         // 3072
// softmax in log2 domain: Q pre-scaled by 1/sqrt(64)*log2(e) in the QKV GEMM
#define ATT_C 0.18033688011112042f

typedef unsigned short u16;
typedef __bf16 bf16x8 __attribute__((ext_vector_type(8)));
typedef float f32x4 __attribute__((ext_vector_type(4)));
typedef float f32x16 __attribute__((ext_vector_type(16)));
typedef u16 u16x4 __attribute__((ext_vector_type(4)));
typedef u16 u16x8 __attribute__((ext_vector_type(8)));

__device__ __forceinline__ u16 f2bf(float f) {
  union { float f; unsigned u; } v; v.f = f;
  unsigned r = v.u + 0x7fffu + ((v.u >> 16) & 1u);
  return (u16)(r >> 16);
}

__device__ __forceinline__ void async_copy16(void* lds, const void* g) {
  __builtin_amdgcn_global_load_lds((__attribute__((address_space(1))) void*)(g),
                                   (__attribute__((address_space(3))) void*)(lds),
                                   16, 0, 0);
}

// ---------------- fused fp32 -> bf16 cast (3 inputs, contiguous dst) -------
__global__ __launch_bounds__(256) void cast3_f32_bf16(
    const float* __restrict__ s0, const float* __restrict__ s1,
    const float* __restrict__ s2, u16* __restrict__ dst,
    int n0, int n01, int ntot4) {
  int i = blockIdx.x * 256 + threadIdx.x;
  if (i >= ntot4) return;
  int e = i * 4;
  const float* s; int off;
  if (e < n0) { s = s0; off = 0; }
  else if (e < n01) { s = s1; off = n0; }
  else { s = s2; off = n01; }
  float4 v = *reinterpret_cast<const float4*>(s + (e - off));
  u16x4 o = {f2bf(v.x), f2bf(v.y), f2bf(v.z), f2bf(v.w)};
  *reinterpret_cast<u16x4*>(dst + e) = o;
}

// ------- 128x256 4-phase counted-vmcnt GEMM ---------------------------------
// C[M][N] = A[M][K]*B[N][K]^T. MODE 0: bf16 out, Q cols (< D_DIM) scaled by
// ATT_C. MODE 1: f32 out + bias.
// 512 thr = 8 waves (2M x 4N), per-wave C = 64x64, acc[4][4]. BK=64.
// LDS per buffer: A 128x64 (16KB) + B 256x64 (32KB) = 48KB; x2 = 96KB.
// K-tile t -> buf t&1. Per tile, 2 compute phases:
//  p1: read A03(8)+B01(4); stage B(t+1)->buf^1; barrier; 16 MFMA; barrier.
//  p2: read B23(4); stage A(t+2)->buf (A(t) dead after p1); barrier;
//      16 MFMA; vmcnt(2) [drains B(t+1), leaves A(t+2)]; barrier.
// st_16x32 swizzle on stage-source and ds_read (row bit2 XOR col bit4).
template <int OUT_F32_BIAS>
__global__ __launch_bounds__(512, 1) void gemm_bt8b(
    const u16* __restrict__ A, const u16* __restrict__ Bm,
    u16* __restrict__ Cb, float* __restrict__ Cf, const float* __restrict__ bias,
    int M, int N, int K) {
  extern __shared__ u16 sm[];   // [c][A 8192 u16][B 16384 u16], c stride 24576

  const int tid = threadIdx.x;
  const int lane = tid & 63, wid = tid >> 6;
  const int wr = wid >> 2, wc = wid & 3;        // 2M x 4N
  const int l15 = lane & 15, lg = lane >> 4;
  const int xr = ((l15 >> 2) & 1) << 4;         // read-side swizzle bit

  // XCD swizzle (nwg % 8 == 0)
  const int nwg = gridDim.x * gridDim.y;
  const int lin = blockIdx.y * gridDim.x + blockIdx.x;
  const int swz = (lin & 7) * (nwg >> 3) + (lin >> 3);
  const int bx = swz % gridDim.x, by = swz / gridDim.x;
  const int m0 = by * 128, n0 = bx * 256;

  const int srow = tid >> 3;                          // 0..63
  const int kxs = ((tid & 7) * 8) ^ (((tid >> 5) & 1) << 4);
  const u16* gA = A + (size_t)(m0 + srow) * K + kxs;
  const u16* gB = Bm + (size_t)(n0 + srow) * K + kxs;

#define STGA(tk_, c_)                                                           \
  {                                                                             \
    _Pragma("unroll") for (int p = 0; p < 2; ++p)                               \
      async_copy16(sm + (c_) * 24576 + p * 4096 + tid * 8,                      \
                   gA + (size_t)(p * 64) * K + (size_t)(tk_) * 64);             \
  }
#define STGB(tk_, c_)                                                           \
  {                                                                             \
    _Pragma("unroll") for (int p = 0; p < 4; ++p)                               \
      async_copy16(sm + (c_) * 24576 + 8192 + p * 4096 + tid * 8,               \
                   gB + (size_t)(p * 64) * K + (size_t)(tk_) * 64);             \
  }
#define LDA_(mt_, kk_, c_)                                                      \
  (*reinterpret_cast<const bf16x8*>(sm + (c_) * 24576 +                         \
      (wr * 64 + (mt_) * 16 + l15) * 64 + (((kk_) * 32 + lg * 8) ^ xr)))
#define LDB_(nt_, kk_, c_)                                                      \
  (*reinterpret_cast<const bf16x8*>(sm + (c_) * 24576 + 8192 +                  \
      (wc * 64 + (nt_) * 16 + l15) * 64 + (((kk_) * 32 + lg * 8) ^ xr)))

  f32x4 acc[4][4];
#pragma unroll
  for (int i = 0; i < 4; i++)
#pragma unroll
    for (int j = 0; j < 4; j++) acc[i][j] = (f32x4){0.f, 0.f, 0.f, 0.f};

  const int NT = K >> 6;   // 16

  STGA(0, 0) STGB(0, 0) STGA(1, 1)
  asm volatile("s_waitcnt vmcnt(2)" ::: "memory");
  __builtin_amdgcn_sched_barrier(0);
  __builtin_amdgcn_s_barrier();

  for (int t = 0; t < NT; ++t) {
    const int c = t & 1;
    bf16x8 a03[4][2], b01[2][2], b23[2][2];
    // ---- p1: read A03(8) + B01(4); stage B(t+1) -> c^1
#pragma unroll
    for (int mt = 0; mt < 4; ++mt) {
      a03[mt][0] = LDA_(mt, 0, c);
      a03[mt][1] = LDA_(mt, 1, c);
    }
#pragma unroll
    for (int nt = 0; nt < 2; ++nt) {
      b01[nt][0] = LDB_(nt, 0, c);
      b01[nt][1] = LDB_(nt, 1, c);
    }
    if (t + 1 < NT) STGB(t + 1, c ^ 1)
    __builtin_amdgcn_s_barrier();
    asm volatile("s_waitcnt lgkmcnt(0)" ::: "memory");
    __builtin_amdgcn_sched_barrier(0);
    __builtin_amdgcn_s_setprio(1);
#pragma unroll
    for (int mt = 0; mt < 4; ++mt)
#pragma unroll
      for (int nt = 0; nt < 2; ++nt)
#pragma unroll
        for (int kk = 0; kk < 2; ++kk)
          acc[mt][nt] = __builtin_amdgcn_mfma_f32_16x16x32_bf16(
              a03[mt][kk], b01[nt][kk], acc[mt][nt], 0, 0, 0);
    __builtin_amdgcn_s_setprio(0);
    __builtin_amdgcn_s_barrier();
    // ---- p2: read B23(4); stage A(t+2) -> c (A(t) dead since p1)
#pragma unroll
    for (int nt = 0; nt < 2; ++nt) {
      b23[nt][0] = LDB_(nt + 2, 0, c);
      b23[nt][1] = LDB_(nt + 2, 1, c);
    }
    if (t + 2 < NT) STGA(t + 2, c)
    __builtin_amdgcn_s_barrier();
    asm volatile("s_waitcnt lgkmcnt(0)" ::: "memory");
    __builtin_amdgcn_sched_barrier(0);
    __builtin_amdgcn_s_setprio(1);
#pragma unroll
    for (int mt = 0; mt < 4; ++mt)
#pragma unroll
      for (int nt = 0; nt < 2; ++nt)
#pragma unroll
        for (int kk = 0; kk < 2; ++kk)
          acc[mt][nt + 2] = __builtin_amdgcn_mfma_f32_16x16x32_bf16(
              a03[mt][kk], b23[nt][kk], acc[mt][nt + 2], 0, 0, 0);
    __builtin_amdgcn_s_setprio(0);
    if (t + 1 < NT) {
      if (t + 2 < NT) {
        asm volatile("s_waitcnt vmcnt(2)" ::: "memory");
      } else {
        asm volatile("s_waitcnt vmcnt(0)" ::: "memory");
      }
      __builtin_amdgcn_sched_barrier(0);
    }
    __builtin_amdgcn_s_barrier();
  }

  // epilogue
  const float qsc = (!OUT_F32_BIAS && n0 < D_DIM) ? ATT_C : 1.0f;
#pragma unroll
  for (int mt = 0; mt < 4; ++mt) {
#pragma unroll
    for (int r = 0; r < 4; ++r) {
      const int row = m0 + wr * 64 + mt * 16 + lg * 4 + r;
#pragma unroll
      for (int nt = 0; nt < 4; ++nt) {
        const int col = n0 + wc * 64 + nt * 16 + l15;
        if (OUT_F32_BIAS) {
          Cf[(size_t)row * N + col] = acc[mt][nt][r] + bias[col];
        } else {
          Cb[(size_t)row * N + col] = f2bf(acc[mt][nt][r] * qsc);
        }
      }
    }
  }
#undef STGA
#undef STGB
#undef LDA_
#undef LDB_
}

// ---------------- causal flash attention (R11 best-known) -------------------
// Swapped-operand 32x32 (lane owns q row), fixed-shift softmax (Q pre-scaled
// in GEMM; p = exp2(S) directly, no max tracking), row-sum via ones-MFMA,
// anti-diagonal pair (qtA=px, qtB=15-px) for uniform work, KVBLK=128 staging,
// XOR-swizzled K, padded V fragments.
#define VF_STRIDE 24
#define VF_FRAG (32 * VF_STRIDE)

__device__ __forceinline__ void process32(
    const bf16x8 (&qf)[4], f32x16 (&o)[2], f32x16& lacc,
    int q0w, int kv0, int l31, int hi, bool needMask, const bf16x8 onesf,
    const u16* __restrict__ Ks, const u16* __restrict__ Vf) {
  f32x16 s[2];
#pragma unroll
  for (int kb = 0; kb < 2; ++kb)
#pragma unroll
    for (int r = 0; r < 16; ++r) s[kb][r] = 0.f;

  __builtin_amdgcn_s_setprio(1);
#pragma unroll
  for (int kb = 0; kb < 2; ++kb) {
#pragma unroll
    for (int ks = 0; ks < 4; ++ks) {
      const int row = kb * 32 + l31;
      bf16x8 kf = *reinterpret_cast<const bf16x8*>(
          &Ks[row * 64 + ((((ks << 1) | hi)) ^ (l31 & 7)) * 8]);
      s[kb] = __builtin_amdgcn_mfma_f32_32x32x16_bf16(kf, qf[ks], s[kb], 0, 0, 0);
    }
  }
  __builtin_amdgcn_s_setprio(0);

  if (needMask) {
    const int q = q0w + l31;
#pragma unroll
    for (int kb = 0; kb < 2; ++kb)
#pragma unroll
      for (int r = 0; r < 16; ++r) {
        const int kv = kv0 + kb * 32 + (r & 3) + ((r >> 2) << 3) + (hi << 2);
        if (kv > q) s[kb][r] = -1e30f;
      }
  }
#pragma unroll
  for (int kb = 0; kb < 2; ++kb)
#pragma unroll
    for (int r = 0; r < 16; ++r)
      s[kb][r] = __builtin_amdgcn_exp2f(s[kb][r]);

  union Frag { unsigned u[4]; bf16x8 v; };
  Frag pf[4];
#pragma unroll
  for (int kb = 0; kb < 2; ++kb)
#pragma unroll
    for (int g = 0; g < 2; ++g) {
#pragma unroll
      for (int t2 = 0; t2 < 2; ++t2) {
        unsigned x, y;
        asm("v_cvt_pk_bf16_f32 %0, %1, %2"
            : "=v"(x) : "v"(s[kb][g * 8 + t2 * 2]), "v"(s[kb][g * 8 + t2 * 2 + 1]));
        asm("v_cvt_pk_bf16_f32 %0, %1, %2"
            : "=v"(y) : "v"(s[kb][g * 8 + t2 * 2 + 4]), "v"(s[kb][g * 8 + t2 * 2 + 5]));
        asm("v_permlane32_swap_b32 %0, %1" : "+v"(x), "+v"(y));
        pf[kb * 2 + g].u[t2] = x;
        pf[kb * 2 + g].u[t2 + 2] = y;
      }
    }

  __builtin_amdgcn_s_setprio(1);
#pragma unroll
  for (int ks = 0; ks < 4; ++ks) {
    lacc = __builtin_amdgcn_mfma_f32_32x32x16_bf16(onesf, pf[ks].v, lacc, 0, 0, 0);
#pragma unroll
    for (int db = 0; db < 2; ++db) {
      bf16x8 vf = *reinterpret_cast<const bf16x8*>(
          &Vf[(ks * 2 + db) * VF_FRAG + l31 * VF_STRIDE + hi * 8]);
      o[db] = __builtin_amdgcn_mfma_f32_32x32x16_bf16(vf, pf[ks].v, o[db], 0, 0, 0);
    }
  }
  __builtin_amdgcn_s_setprio(0);
}

__global__ __launch_bounds__(256, 2) void attn_kernel(
    const u16* __restrict__ qkv, u16* __restrict__ aout) {
  __shared__ __attribute__((aligned(16))) u16 Ks[128 * 64];
  __shared__ __attribute__((aligned(16))) u16 Vf[16 * VF_FRAG];

  const int tid = threadIdx.x;
  const int lane = tid & 63, w = tid >> 6;
  const int l31 = lane & 31, hi = lane >> 5;

  const int nwg = gridDim.x * gridDim.y;          // 512
  const int lin = blockIdx.y * gridDim.x + blockIdx.x;
  const int swz = (lin & 7) * (nwg >> 3) + (lin >> 3);
  const int px = swz % gridDim.x;
  const int bh = swz / gridDim.x;
  const int b = bh >> 4, h = bh & 15;
  const int qtA = px, qtB = 15 - px;
  const int q0A = qtA * 128 + w * 32, q0B = qtB * 128 + w * 32;

  bf16x8 qfA[4], qfB[4];
  {
    const u16* pA = qkv + ((size_t)(q0A + l31) * B_DIM + b) * QKV_N + h * HD + hi * 8;
    const u16* pB = qkv + ((size_t)(q0B + l31) * B_DIM + b) * QKV_N + h * HD + hi * 8;
#pragma unroll
    for (int ks = 0; ks < 4; ++ks) {
      qfA[ks] = *reinterpret_cast<const bf16x8*>(pA + ks * 16);
      qfB[ks] = *reinterpret_cast<const bf16x8*>(pB + ks * 16);
    }
  }

  bf16x8 onesf;
  {
    union { u16 u[8]; bf16x8 v; } ou;
#pragma unroll
    for (int i = 0; i < 8; ++i) ou.u[i] = 0x3F80;
    onesf = ou.v;
  }

  f32x16 oA[2], oB[2], laccA, laccB;
#pragma unroll
  for (int r = 0; r < 16; ++r) { laccA[r] = 0.f; laccB[r] = 0.f; }
#pragma unroll
  for (int db = 0; db < 2; ++db)
#pragma unroll
    for (int r = 0; r < 16; ++r) { oA[db][r] = 0.f; oB[db][r] = 0.f; }

  const int srow = tid >> 3;
  const int scol = (tid & 7) * 8;
  const int csw = (tid & 7) ^ (srow & 7);

  for (int kt2 = 0; kt2 <= qtB; ++kt2) {
    const int base = kt2 * 128;
#pragma unroll
    for (int p = 0; p < 4; ++p) {
      const u16* gK = qkv + ((size_t)(base + p * 32 + srow) * B_DIM + b) * QKV_N +
                      D_DIM + h * HD + csw * 8;
      async_copy16(Ks + tid * 8 + p * 2048, gK);
    }
    u16x8 vv[4];
#pragma unroll
    for (int p = 0; p < 4; ++p) {
      const u16* gV = qkv + ((size_t)(base + p * 32 + srow) * B_DIM + b) * QKV_N +
                      2 * D_DIM + h * HD + scol;
      vv[p] = *reinterpret_cast<const u16x8*>(gV);
    }
#pragma unroll
    for (int p = 0; p < 4; ++p) {
      const int kvl = p * 32 + srow;
      const int fb = (kvl >> 4) * 2;
      const int e16 = kvl & 15;
#pragma unroll
      for (int jj = 0; jj < 8; ++jj) {
        const int j = (jj + srow) & 7;
        const int d = scol + j;
        Vf[(fb + (d >> 5)) * VF_FRAG + (d & 31) * VF_STRIDE + e16] = vv[p][j];
      }
    }
    __syncthreads();

#pragma unroll
    for (int half = 0; half < 2; ++half) {
      const int kv0 = base + half * 64;
      const u16* Kh = Ks + half * (64 * 64);
      const u16* Vh = Vf + half * 8 * VF_FRAG;
      if (kv0 <= q0A + 31)
        process32(qfA, oA, laccA, q0A, kv0, l31, hi, kv0 + 63 > q0A, onesf, Kh, Vh);
      if (kv0 <= q0B + 31)
        process32(qfB, oB, laccB, q0B, kv0, l31, hi, kv0 + 63 > q0B, onesf, Kh, Vh);
    }
    __syncthreads();
  }

#pragma unroll
  for (int t = 0; t < 2; ++t) {
    const float inv = 1.0f / (t == 0 ? laccA[0] : laccB[0]);
    const int q0w = t == 0 ? q0A : q0B;
    f32x16* o = t == 0 ? oA : oB;
    u16* orow = aout + ((size_t)(q0w + l31) * B_DIM + b) * D_DIM + h * HD;
#pragma unroll
    for (int db = 0; db < 2; ++db)
#pragma unroll
      for (int rq = 0; rq < 4; ++rq) {
        u16x4 o4;
#pragma unroll
        for (int e = 0; e < 4; ++e) o4[e] = f2bf(o[db][rq * 4 + e] * inv);
        *reinterpret_cast<u16x4*>(orow + db * 32 + rq * 8 + hi * 4) = o4;
      }
  }
}

// ---------------- launch ----------------
extern "C" void kernel_launch(void* const* d_in, const int* in_sizes, int n_in,
                              void* d_out, int out_size, void* d_ws, size_t ws_size,
                              hipStream_t stream) {
  (void)in_sizes; (void)n_in; (void)out_size; (void)ws_size;
  const float* x = (const float*)d_in[0];
  const float* Wqkv = (const float*)d_in[1];
  const float* Wout = (const float*)d_in[2];
  const float* bout = (const float*)d_in[3];
  float* out = (float*)d_out;

  u16* xb = (u16*)d_ws;                               // [8192][1024]
  u16* wqkvb = xb + (size_t)MROWS * D_DIM;            // [3072][1024]
  u16* woutb = wqkvb + (size_t)QKV_N * D_DIM;         // [1024][1024]
  u16* qkv = woutb + (size_t)D_DIM * D_DIM;           // [8192][3072]
  u16* aout = qkv + (size_t)MROWS * QKV_N;            // [8192][1024]

  {
    const int n0 = MROWS * D_DIM;
    const int n01 = n0 + QKV_N * D_DIM;
    const int ntot = n01 + D_DIM * D_DIM;
    const int n4 = ntot / 4;
    cast3_f32_bf16<<<(n4 + 255) / 256, 256, 0, stream>>>(
        x, Wqkv, Wout, xb, n0, n01, n4);
  }

  // QKV GEMM: 128x256 4-phase, 96 KiB dynamic LDS, 768 blocks (3.0 rounds)
  hipFuncSetAttribute((const void*)gemm_bt8b<0>,
                      hipFuncAttributeMaxDynamicSharedMemorySize, 98304);
  gemm_bt8b<0><<<dim3(QKV_N / 256, MROWS / 128), 512, 98304, stream>>>(
      xb, wqkvb, qkv, nullptr, nullptr, MROWS, QKV_N, D_DIM);

  attn_kernel<<<dim3(8, B_DIM * H_NUM), 256, 0, stream>>>(qkv, aout);

  // out-proj: 128x256 4-phase, 256 blocks (exactly 1.0 rounds), f32+bias out
  hipFuncSetAttribute((const void*)gemm_bt8b<1>,
                      hipFuncAttributeMaxDynamicSharedMemorySize, 98304);
  gemm_bt8b<1><<<dim3(D_DIM / 256, MROWS / 128), 512, 98304, stream>>>(
      aout, woutb, nullptr, out, bout, MROWS, D_DIM, D_DIM);
}

// Round 22
// 158.610 us; speedup vs baseline: 1.1256x; 1.1256x over previous
//
#include <hip/hip_runtime.h>
#include <stdint.h>

// Problem constants
#define T_DIM 2048
#define B_DIM 4
#define D_DIM 1024
#define H_NUM 16
#define HD 64
#define MROWS (T_DIM * B_DIM)     // 8192 flattened (t*B+b) rows
#define QKV_N (3 * D_DIM)         // 3072
// softmax in log2 domain: Q pre-scaled by 1/sqrt(64)*log2(e) in the QKV GEMM
#define ATT_C 0.18033688011112042f

typedef unsigned short u16;
typedef __bf16 bf16x8 __attribute__((ext_vector_type(8)));
typedef float f32x4 __attribute__((ext_vector_type(4)));
typedef float f32x16 __attribute__((ext_vector_type(16)));
typedef u16 u16x4 __attribute__((ext_vector_type(4)));
typedef u16 u16x8 __attribute__((ext_vector_type(8)));
typedef unsigned u32x2 __attribute__((ext_vector_type(2)));

__device__ __forceinline__ u16 f2bf(float f) {
  union { float f; unsigned u; } v; v.f = f;
  unsigned r = v.u + 0x7fffu + ((v.u >> 16) & 1u);
  return (u16)(r >> 16);
}

__device__ __forceinline__ void async_copy16(void* lds, const void* g) {
  __builtin_amdgcn_global_load_lds((__attribute__((address_space(1))) void*)(g),
                                   (__attribute__((address_space(3))) void*)(lds),
                                   16, 0, 0);
}

// ---------------- fused fp32 -> bf16 cast (3 inputs, contiguous dst) -------
__global__ __launch_bounds__(256) void cast3_f32_bf16(
    const float* __restrict__ s0, const float* __restrict__ s1,
    const float* __restrict__ s2, u16* __restrict__ dst,
    int n0, int n01, int ntot4) {
  int i = blockIdx.x * 256 + threadIdx.x;
  if (i >= ntot4) return;
  int e = i * 4;
  const float* s; int off;
  if (e < n0) { s = s0; off = 0; }
  else if (e < n01) { s = s1; off = n0; }
  else { s = s2; off = n01; }
  float4 v = *reinterpret_cast<const float4*>(s + (e - off));
  u16x4 o = {f2bf(v.x), f2bf(v.y), f2bf(v.z), f2bf(v.w)};
  *reinterpret_cast<u16x4*>(dst + e) = o;
}

// ------- 128x256 4-phase counted-vmcnt GEMM (unchanged, verified) ----------
template <int OUT_F32_BIAS>
__global__ __launch_bounds__(512, 1) void gemm_bt8b(
    const u16* __restrict__ A, const u16* __restrict__ Bm,
    u16* __restrict__ Cb, float* __restrict__ Cf, const float* __restrict__ bias,
    int M, int N, int K) {
  extern __shared__ u16 sm[];   // [c][A 8192 u16][B 16384 u16], c stride 24576

  const int tid = threadIdx.x;
  const int lane = tid & 63, wid = tid >> 6;
  const int wr = wid >> 2, wc = wid & 3;        // 2M x 4N
  const int l15 = lane & 15, lg = lane >> 4;
  const int xr = ((l15 >> 2) & 1) << 4;

  const int nwg = gridDim.x * gridDim.y;
  const int lin = blockIdx.y * gridDim.x + blockIdx.x;
  const int swz = (lin & 7) * (nwg >> 3) + (lin >> 3);
  const int bx = swz % gridDim.x, by = swz / gridDim.x;
  const int m0 = by * 128, n0 = bx * 256;

  const int srow = tid >> 3;                          // 0..63
  const int kxs = ((tid & 7) * 8) ^ (((tid >> 5) & 1) << 4);
  const u16* gA = A + (size_t)(m0 + srow) * K + kxs;
  const u16* gB = Bm + (size_t)(n0 + srow) * K + kxs;

#define STGA(tk_, c_)                                                           \
  {                                                                             \
    _Pragma("unroll") for (int p = 0; p < 2; ++p)                               \
      async_copy16(sm + (c_) * 24576 + p * 4096 + tid * 8,                      \
                   gA + (size_t)(p * 64) * K + (size_t)(tk_) * 64);             \
  }
#define STGB(tk_, c_)                                                           \
  {                                                                             \
    _Pragma("unroll") for (int p = 0; p < 4; ++p)                               \
      async_copy16(sm + (c_) * 24576 + 8192 + p * 4096 + tid * 8,               \
                   gB + (size_t)(p * 64) * K + (size_t)(tk_) * 64);             \
  }
#define LDA_(mt_, kk_, c_)                                                      \
  (*reinterpret_cast<const bf16x8*>(sm + (c_) * 24576 +                         \
      (wr * 64 + (mt_) * 16 + l15) * 64 + (((kk_) * 32 + lg * 8) ^ xr)))
#define LDB_(nt_, kk_, c_)                                                      \
  (*reinterpret_cast<const bf16x8*>(sm + (c_) * 24576 + 8192 +                  \
      (wc * 64 + (nt_) * 16 + l15) * 64 + (((kk_) * 32 + lg * 8) ^ xr)))

  f32x4 acc[4][4];
#pragma unroll
  for (int i = 0; i < 4; i++)
#pragma unroll
    for (int j = 0; j < 4; j++) acc[i][j] = (f32x4){0.f, 0.f, 0.f, 0.f};

  const int NT = K >> 6;   // 16

  STGA(0, 0) STGB(0, 0) STGA(1, 1)
  asm volatile("s_waitcnt vmcnt(2)" ::: "memory");
  __builtin_amdgcn_sched_barrier(0);
  __builtin_amdgcn_s_barrier();

  for (int t = 0; t < NT; ++t) {
    const int c = t & 1;
    bf16x8 a03[4][2], b01[2][2], b23[2][2];
#pragma unroll
    for (int mt = 0; mt < 4; ++mt) {
      a03[mt][0] = LDA_(mt, 0, c);
      a03[mt][1] = LDA_(mt, 1, c);
    }
#pragma unroll
    for (int nt = 0; nt < 2; ++nt) {
      b01[nt][0] = LDB_(nt, 0, c);
      b01[nt][1] = LDB_(nt, 1, c);
    }
    if (t + 1 < NT) STGB(t + 1, c ^ 1)
    __builtin_amdgcn_s_barrier();
    asm volatile("s_waitcnt lgkmcnt(0)" ::: "memory");
    __builtin_amdgcn_sched_barrier(0);
    __builtin_amdgcn_s_setprio(1);
#pragma unroll
    for (int mt = 0; mt < 4; ++mt)
#pragma unroll
      for (int nt = 0; nt < 2; ++nt)
#pragma unroll
        for (int kk = 0; kk < 2; ++kk)
          acc[mt][nt] = __builtin_amdgcn_mfma_f32_16x16x32_bf16(
              a03[mt][kk], b01[nt][kk], acc[mt][nt], 0, 0, 0);
    __builtin_amdgcn_s_setprio(0);
    __builtin_amdgcn_s_barrier();
#pragma unroll
    for (int nt = 0; nt < 2; ++nt) {
      b23[nt][0] = LDB_(nt + 2, 0, c);
      b23[nt][1] = LDB_(nt + 2, 1, c);
    }
    if (t + 2 < NT) STGA(t + 2, c)
    __builtin_amdgcn_s_barrier();
    asm volatile("s_waitcnt lgkmcnt(0)" ::: "memory");
    __builtin_amdgcn_sched_barrier(0);
    __builtin_amdgcn_s_setprio(1);
#pragma unroll
    for (int mt = 0; mt < 4; ++mt)
#pragma unroll
      for (int nt = 0; nt < 2; ++nt)
#pragma unroll
        for (int kk = 0; kk < 2; ++kk)
          acc[mt][nt + 2] = __builtin_amdgcn_mfma_f32_16x16x32_bf16(
              a03[mt][kk], b23[nt][kk], acc[mt][nt + 2], 0, 0, 0);
    __builtin_amdgcn_s_setprio(0);
    if (t + 1 < NT) {
      if (t + 2 < NT) {
        asm volatile("s_waitcnt vmcnt(2)" ::: "memory");
      } else {
        asm volatile("s_waitcnt vmcnt(0)" ::: "memory");
      }
      __builtin_amdgcn_sched_barrier(0);
    }
    __builtin_amdgcn_s_barrier();
  }

  const float qsc = (!OUT_F32_BIAS && n0 < D_DIM) ? ATT_C : 1.0f;
#pragma unroll
  for (int mt = 0; mt < 4; ++mt) {
#pragma unroll
    for (int r = 0; r < 4; ++r) {
      const int row = m0 + wr * 64 + mt * 16 + lg * 4 + r;
#pragma unroll
      for (int nt = 0; nt < 4; ++nt) {
        const int col = n0 + wc * 64 + nt * 16 + l15;
        if (OUT_F32_BIAS) {
          Cf[(size_t)row * N + col] = acc[mt][nt][r] + bias[col];
        } else {
          Cb[(size_t)row * N + col] = f2bf(acc[mt][nt][r] * qsc);
        }
      }
    }
  }
#undef STGA
#undef STGB
#undef LDA_
#undef LDB_
}

// ---------------- causal flash attention: tr-read V, corrected -------------
// V LDS layout (per 64-kv half, 4096 u16): subtile s=(kv>>2)*4+(d>>4) of
// [4][16] row-major (r=kv&3, c=d&15) at element offset s*64. 8-u16 chunks
// are d-contiguous -> staged via global_load_lds with inverse-permuted
// source. Reads: ds_read_b64_tr_b16 with 8B-strided per-lane addresses
// (m162 model): lane addr = (l>>5)*1024 + ((l>>4)&1)*128 + (l&15)*8 bytes,
// + ks*2048 + db*256 + jhalf*512. Each 16-lane group spans one 128B subtile;
// lane l gets column l&15 -> elem j = V[ks*16+hi*8+jhalf*4+j][db*32+l31],
// exactly the 32x32 MFMA A-operand fragment (layout verified by the working
// padded-Vf kernel).

__device__ __forceinline__ void process32(
    const bf16x8 (&qf)[4], f32x16 (&o)[2], f32x16& lacc,
    int q0w, int kv0, int l31, int hi, bool needMask, const bf16x8 onesf,
    const u16* __restrict__ Ks, unsigned vh_lane) {
  f32x16 s[2];
#pragma unroll
  for (int kb = 0; kb < 2; ++kb)
#pragma unroll
    for (int r = 0; r < 16; ++r) s[kb][r] = 0.f;

  // S^T[kv][q] = K . Q^T  (Q pre-scaled)
  __builtin_amdgcn_s_setprio(1);
#pragma unroll
  for (int kb = 0; kb < 2; ++kb) {
#pragma unroll
    for (int ks = 0; ks < 4; ++ks) {
      const int row = kb * 32 + l31;
      bf16x8 kf = *reinterpret_cast<const bf16x8*>(
          &Ks[row * 64 + ((((ks << 1) | hi)) ^ (l31 & 7)) * 8]);
      s[kb] = __builtin_amdgcn_mfma_f32_32x32x16_bf16(kf, qf[ks], s[kb], 0, 0, 0);
    }
  }
  __builtin_amdgcn_s_setprio(0);

  if (needMask) {
    const int q = q0w + l31;
#pragma unroll
    for (int kb = 0; kb < 2; ++kb)
#pragma unroll
      for (int r = 0; r < 16; ++r) {
        const int kv = kv0 + kb * 32 + (r & 3) + ((r >> 2) << 3) + (hi << 2);
        if (kv > q) s[kb][r] = -1e30f;
      }
  }
#pragma unroll
  for (int kb = 0; kb < 2; ++kb)
#pragma unroll
    for (int r = 0; r < 16; ++r)
      s[kb][r] = __builtin_amdgcn_exp2f(s[kb][r]);

  // repack P (f32, S^T layout) -> bf16 B-frags
  union Frag { unsigned u[4]; bf16x8 v; };
  Frag pf[4];
#pragma unroll
  for (int kb = 0; kb < 2; ++kb)
#pragma unroll
    for (int g = 0; g < 2; ++g) {
#pragma unroll
      for (int t2 = 0; t2 < 2; ++t2) {
        unsigned x, y;
        asm("v_cvt_pk_bf16_f32 %0, %1, %2"
            : "=v"(x) : "v"(s[kb][g * 8 + t2 * 2]), "v"(s[kb][g * 8 + t2 * 2 + 1]));
        asm("v_cvt_pk_bf16_f32 %0, %1, %2"
            : "=v"(y) : "v"(s[kb][g * 8 + t2 * 2 + 4]), "v"(s[kb][g * 8 + t2 * 2 + 5]));
        asm("v_permlane32_swap_b32 %0, %1" : "+v"(x), "+v"(y));
        pf[kb * 2 + g].u[t2] = x;
        pf[kb * 2 + g].u[t2 + 2] = y;
      }
    }

  // O^T += V^T . P via hardware transpose reads; lacc += ones . P
#pragma unroll
  for (int ks = 0; ks < 4; ++ks) {
    u32x2 t00, t01, t10, t11;
    const unsigned a = vh_lane + ks * 2048;
    asm volatile("ds_read_b64_tr_b16 %0, %1" : "=v"(t00) : "v"(a) : "memory");
    asm volatile("ds_read_b64_tr_b16 %0, %1 offset:512" : "=v"(t01) : "v"(a) : "memory");
    asm volatile("ds_read_b64_tr_b16 %0, %1 offset:256" : "=v"(t10) : "v"(a) : "memory");
    asm volatile("ds_read_b64_tr_b16 %0, %1 offset:768" : "=v"(t11) : "v"(a) : "memory");
    asm volatile("s_waitcnt lgkmcnt(0)" ::: "memory");
    __builtin_amdgcn_sched_barrier(0);
    union VF { u32x2 h2[2]; bf16x8 v; } u0, u1;
    u0.h2[0] = t00; u0.h2[1] = t01;   // db=0: j0..3, j4..7
    u1.h2[0] = t10; u1.h2[1] = t11;   // db=1
    __builtin_amdgcn_s_setprio(1);
    lacc = __builtin_amdgcn_mfma_f32_32x32x16_bf16(onesf, pf[ks].v, lacc, 0, 0, 0);
    o[0] = __builtin_amdgcn_mfma_f32_32x32x16_bf16(u0.v, pf[ks].v, o[0], 0, 0, 0);
    o[1] = __builtin_amdgcn_mfma_f32_32x32x16_bf16(u1.v, pf[ks].v, o[1], 0, 0, 0);
    __builtin_amdgcn_s_setprio(0);
  }
}

__global__ __launch_bounds__(256, 2) void attn_kernel(
    const u16* __restrict__ qkv, u16* __restrict__ aout) {
  __shared__ __attribute__((aligned(16))) u16 Ks[128 * 64];   // swizzled rows
  __shared__ __attribute__((aligned(16))) u16 Vs[8192];       // subtiled V

  const int tid = threadIdx.x;
  const int lane = tid & 63, w = tid >> 6;
  const int l31 = lane & 31, hi = lane >> 5;

  const int nwg = gridDim.x * gridDim.y;          // 512
  const int lin = blockIdx.y * gridDim.x + blockIdx.x;
  const int swz = (lin & 7) * (nwg >> 3) + (lin >> 3);
  const int px = swz % gridDim.x;
  const int bh = swz / gridDim.x;
  const int b = bh >> 4, h = bh & 15;
  const int qtA = px, qtB = 15 - px;
  const int q0A = qtA * 128 + w * 32, q0B = qtB * 128 + w * 32;

  bf16x8 qfA[4], qfB[4];
  {
    const u16* pA = qkv + ((size_t)(q0A + l31) * B_DIM + b) * QKV_N + h * HD + hi * 8;
    const u16* pB = qkv + ((size_t)(q0B + l31) * B_DIM + b) * QKV_N + h * HD + hi * 8;
#pragma unroll
    for (int ks = 0; ks < 4; ++ks) {
      qfA[ks] = *reinterpret_cast<const bf16x8*>(pA + ks * 16);
      qfB[ks] = *reinterpret_cast<const bf16x8*>(pB + ks * 16);
    }
  }

  bf16x8 onesf;
  {
    union { u16 u[8]; bf16x8 v; } ou;
#pragma unroll
    for (int i = 0; i < 8; ++i) ou.u[i] = 0x3F80;
    onesf = ou.v;
  }

  f32x16 oA[2], oB[2], laccA, laccB;
#pragma unroll
  for (int r = 0; r < 16; ++r) { laccA[r] = 0.f; laccB[r] = 0.f; }
#pragma unroll
  for (int db = 0; db < 2; ++db)
#pragma unroll
    for (int r = 0; r < 16; ++r) { oA[db][r] = 0.f; oB[db][r] = 0.f; }

  const int srow = tid >> 3;
  const int csw = (tid & 7) ^ (srow & 7);    // pre-swizzled K source chunk

  // V staging inverse-permute: LDS elem x = s*64 + r*16 + c with
  // kv = (s>>2)*4 + r, d = (s&3)*16 + c; chunk p covers x0 = tid*8 + p*2048.
  int rowoffV[4], dcolV[4];
#pragma unroll
  for (int p = 0; p < 4; ++p) {
    const int x0 = tid * 8 + p * 2048;
    const int halfv = x0 >> 12, xh = x0 & 4095;
    const int s = xh >> 6, r = (xh >> 4) & 3, c0 = xh & 15;
    rowoffV[p] = halfv * 64 + (s >> 2) * 4 + r;
    dcolV[p] = (s & 3) * 16 + c0;
  }

  // per-lane tr-read base (bytes): (l>>5)*1024 + ((l>>4)&1)*128 + (l&15)*8
  const unsigned vlane = (unsigned)(lane >> 5) * 1024u +
                         (unsigned)((lane >> 4) & 1) * 128u +
                         (unsigned)(lane & 15) * 8u;
  const unsigned vs0 = (unsigned)(uintptr_t)&Vs[0];

  for (int kt2 = 0; kt2 <= qtB; ++kt2) {
    const int base = kt2 * 128;
    // stage K (swizzled source, linear dest)
#pragma unroll
    for (int p = 0; p < 4; ++p) {
      const u16* gK = qkv + ((size_t)(base + p * 32 + srow) * B_DIM + b) * QKV_N +
                      D_DIM + h * HD + csw * 8;
      async_copy16(Ks + tid * 8 + p * 2048, gK);
    }
    // stage V (inverse-permuted source, linear subtiled dest)
#pragma unroll
    for (int p = 0; p < 4; ++p) {
      const u16* gV = qkv + ((size_t)(base + rowoffV[p]) * B_DIM + b) * QKV_N +
                      2 * D_DIM + h * HD + dcolV[p];
      async_copy16(Vs + tid * 8 + p * 2048, gV);
    }
    __syncthreads();

#pragma unroll
    for (int half = 0; half < 2; ++half) {
      const int kv0 = base + half * 64;
      const u16* Kh = Ks + half * (64 * 64);
      const unsigned vh_lane = vs0 + half * 8192 + vlane;
      if (kv0 <= q0A + 31)
        process32(qfA, oA, laccA, q0A, kv0, l31, hi, kv0 + 63 > q0A, onesf, Kh, vh_lane);
      if (kv0 <= q0B + 31)
        process32(qfB, oB, laccB, q0B, kv0, l31, hi, kv0 + 63 > q0B, onesf, Kh, vh_lane);
    }
    __syncthreads();
  }

  // epilogue
#pragma unroll
  for (int t = 0; t < 2; ++t) {
    const float inv = 1.0f / (t == 0 ? laccA[0] : laccB[0]);
    const int q0w = t == 0 ? q0A : q0B;
    f32x16* o = t == 0 ? oA : oB;
    u16* orow = aout + ((size_t)(q0w + l31) * B_DIM + b) * D_DIM + h * HD;
#pragma unroll
    for (int db = 0; db < 2; ++db)
#pragma unroll
      for (int rq = 0; rq < 4; ++rq) {
        u16x4 o4;
#pragma unroll
        for (int e = 0; e < 4; ++e) o4[e] = f2bf(o[db][rq * 4 + e] * inv);
        *reinterpret_cast<u16x4*>(orow + db * 32 + rq * 8 + hi * 4) = o4;
      }
  }
}

// ---------------- launch ----------------
extern "C" void kernel_launch(void* const* d_in, const int* in_sizes, int n_in,
                              void* d_out, int out_size, void* d_ws, size_t ws_size,
                              hipStream_t stream) {
  (void)in_sizes; (void)n_in; (void)out_size; (void)ws_size;
  const float* x = (const float*)d_in[0];
  const float* Wqkv = (const float*)d_in[1];
  const float* Wout = (const float*)d_in[2];
  const float* bout = (const float*)d_in[3];
  float* out = (float*)d_out;

  u16* xb = (u16*)d_ws;                               // [8192][1024]
  u16* wqkvb = xb + (size_t)MROWS * D_DIM;            // [3072][1024]
  u16* woutb = wqkvb + (size_t)QKV_N * D_DIM;         // [1024][1024]
  u16* qkv = woutb + (size_t)D_DIM * D_DIM;           // [8192][3072]
  u16* aout = qkv + (size_t)MROWS * QKV_N;            // [8192][1024]

  {
    const int n0 = MROWS * D_DIM;
    const int n01 = n0 + QKV_N * D_DIM;
    const int ntot = n01 + D_DIM * D_DIM;
    const int n4 = ntot / 4;
    cast3_f32_bf16<<<(n4 + 255) / 256, 256, 0, stream>>>(
        x, Wqkv, Wout, xb, n0, n01, n4);
  }

  hipFuncSetAttribute((const void*)gemm_bt8b<0>,
                      hipFuncAttributeMaxDynamicSharedMemorySize, 98304);
  gemm_bt8b<0><<<dim3(QKV_N / 256, MROWS / 128), 512, 98304, stream>>>(
      xb, wqkvb, qkv, nullptr, nullptr, MROWS, QKV_N, D_DIM);

  attn_kernel<<<dim3(8, B_DIM * H_NUM), 256, 0, stream>>>(qkv, aout);

  hipFuncSetAttribute((const void*)gemm_bt8b<1>,
                      hipFuncAttributeMaxDynamicSharedMemorySize, 98304);
  gemm_bt8b<1><<<dim3(D_DIM / 256, MROWS / 128), 512, 98304, stream>>>(
      aout, woutb, nullptr, out, bout, MROWS, D_DIM, D_DIM);
}